// Round 7
// baseline (485.407 us; speedup 1.0000x reference)
//
#include <hip/hip_runtime.h>

constexpr int DEG   = 31;       // neighbors per node
constexpr int TH    = 16;       // threshold: dp[0..15] + absorbing "over"
constexpr int BLK   = 1024;
constexpr int CHUNK = 65536;    // u8 entries per LDS chunk (64 KB)
constexpr int NCHNK = 16;       // ceil(1e6 / 65536)
constexpr int TBL   = NCHNK * CHUNK;   // 1 MiB padded table

__global__ void zero_out_kernel(float* out) {
    if (threadIdx.x == 0) out[0] = 0.0f;
}

__device__ __forceinline__ float fast_sigmoid(float x) {
    return 1.0f / (1.0f + __expf(-x));
}

// ---- phase 1: u8 table, 4 entries/thread packed into one u32 store ----
__global__ __launch_bounds__(256)
void build_table_kernel(const float* __restrict__ gains,
                        unsigned* __restrict__ tbl4, int n) {
    const int t = blockIdx.x * 256 + threadIdx.x;   // entries 4t..4t+3
    if (t < TBL / 4) {
        unsigned w = 0;
        #pragma unroll
        for (int k = 0; k < 4; ++k) {
            const int i = 4 * t + k;
            const float p = (i < n) ? fast_sigmoid(gains[i]) : 0.0f;
            const unsigned b = __float2uint_rn(p * 255.0f);
            w |= (b & 0xFFu) << (8 * k);
        }
        tbl4[t] = w;
    }
}

// ---- phase 2: double-buffered LDS table stream + gather + DP ----
__global__ __launch_bounds__(BLK)
void pgl_lds_kernel(const float* __restrict__ gains,
                    const int*   __restrict__ nbr,
                    const unsigned char* __restrict__ tbl,
                    float*       __restrict__ out, int n) {
    __shared__ __align__(16) unsigned char buf[2 * CHUNK];   // 131072 B

    const int tid        = threadIdx.x;
    const int blockStart = blockIdx.x * BLK;
    const int i          = blockStart + tid;

    // ---- stage indices through LDS (coalesced), pull to VGPRs ----
    const int rows  = min(BLK, n - blockStart);
    const int elems = rows * DEG;                 // <= 31744 ints = 124 KB, fits
    const int base  = blockStart * DEG;
    {
        const int4* nb4 = (const int4*)(nbr + base);
        int4*       s4  = (int4*)buf;
        int*        s1  = (int*)buf;
        const int nvec = elems >> 2;
        for (int v = tid; v < nvec; v += BLK) s4[v] = nb4[v];
        for (int e = (nvec << 2) + tid; e < elems; e += BLK) s1[e] = nbr[base + e];
    }
    __syncthreads();
    unsigned idx[DEG];
    {
        const int* sidx = (const int*)buf;
        if (i < n) {
            #pragma unroll
            for (int j = 0; j < DEG; ++j) idx[j] = (unsigned)sidx[tid * DEG + j];
        } else {
            #pragma unroll
            for (int j = 0; j < DEG; ++j) idx[j] = 0u;
        }
    }
    __syncthreads();                              // indices consumed; buf free

    // ---- preload chunk 0: 4 x int4 per thread (64 KB / 16 B / 1024) ----
    const int4* t4 = (const int4*)tbl;
    int4 R[4];
    #pragma unroll
    for (int q = 0; q < 4; ++q) R[q] = t4[q * BLK + tid];
    {
        int4* b4 = (int4*)buf;
        #pragma unroll
        for (int q = 0; q < 4; ++q) b4[q * BLK + tid] = R[q];
    }

    unsigned pvu[DEG];
    #pragma unroll
    for (int j = 0; j < DEG; ++j) pvu[j] = 0u;

    for (int c = 0; c < NCHNK; ++c) {
        // issue next chunk's global loads BEFORE the harvest window
        if (c + 1 < NCHNK) {
            const int cb = (c + 1) * (CHUNK / 16);
            #pragma unroll
            for (int q = 0; q < 4; ++q) R[q] = t4[cb + q * BLK + tid];
        }
        __syncthreads();       // publish buf[c&1] (written at end of prev iter)

        const unsigned char* cur = buf + (c & 1) * CHUNK;
        #pragma unroll
        for (int j = 0; j < DEG; ++j) {
            if ((idx[j] >> 16) == (unsigned)c)      // exactly one c per j
                pvu[j] = cur[idx[j] & 0xFFFFu];     // masked ds_read_u8
        }

        // write next chunk into the other buffer (no conflict with readers of cur)
        if (c + 1 < NCHNK) {
            int4* b4 = (int4*)(buf + ((c + 1) & 1) * CHUNK);
            #pragma unroll
            for (int q = 0; q < 4; ++q) b4[q * BLK + tid] = R[q];
        }
    }

    // ---- absorbing-state Poisson-binomial DP ----
    float local = 0.0f;
    if (i < n) {
        const float p0 = fast_sigmoid(gains[i]);    // self stays fp32
        float dp[TH];
        dp[0] = 1.0f;
        #pragma unroll
        for (int k = 1; k < TH; ++k) dp[k] = 0.0f;
        float over = 0.0f;

        #pragma unroll
        for (int j = 0; j <= DEG; ++j) {
            const float pj = (j == 0) ? p0 : (float)pvu[j - 1] * (1.0f / 255.0f);
            if (j >= TH - 1) over = fmaf(dp[TH - 1], pj, over);
            const int kmax = (j + 1 < TH - 1) ? (j + 1) : (TH - 1);
            #pragma unroll
            for (int k = kmax; k >= 1; --k)
                dp[k] = fmaf(pj, dp[k - 1] - dp[k], dp[k]);
            dp[0] = fmaf(-pj, dp[0], dp[0]);
        }
        local = fmaf(0.25f, p0, -over);             // -(loss) contribution
    }

    // ---- reduction: wave shuffle -> (reused) LDS -> one atomic per block ----
    #pragma unroll
    for (int o = 32; o > 0; o >>= 1) local += __shfl_down(local, o, 64);
    __syncthreads();                                // buf reads all done; reuse
    float* s_red = (float*)buf;
    if ((tid & 63) == 0) s_red[tid >> 6] = local;
    __syncthreads();
    if (tid == 0) {
        float s = 0.0f;
        #pragma unroll
        for (int w = 0; w < BLK / 64; ++w) s += s_red[w];
        atomicAdd(out, s);
    }
}

// ---- fallback (ws too small): round-1 direct-gather kernel ----
constexpr int FBLK = 128;
__global__ __launch_bounds__(FBLK)
void pgl_direct_kernel(const float* __restrict__ gains,
                       const int*   __restrict__ nbr,
                       float*       __restrict__ out, int n) {
    __shared__ int s_idx[FBLK * DEG];
    __shared__ float s_red[FBLK / 64];
    const int tid = threadIdx.x;
    const int blockStart = blockIdx.x * FBLK;
    const int rows  = min(FBLK, n - blockStart);
    const int elems = rows * DEG;
    const int base  = blockStart * DEG;
    const int4* nb4 = (const int4*)(nbr + base);
    int4* s4 = (int4*)s_idx;
    const int nvec = elems >> 2;
    for (int v = tid; v < nvec; v += FBLK) s4[v] = nb4[v];
    for (int e = (nvec << 2) + tid; e < elems; e += FBLK) s_idx[e] = nbr[base + e];
    __syncthreads();
    float local = 0.0f;
    const int i = blockStart + tid;
    if (i < n) {
        const int* row = s_idx + tid * DEG;
        float dp[TH];
        dp[0] = 1.0f;
        #pragma unroll
        for (int k = 1; k < TH; ++k) dp[k] = 0.0f;
        float over = 0.0f;
        const float p0 = fast_sigmoid(gains[i]);
        #pragma unroll
        for (int j = 0; j <= DEG; ++j) {
            const float pj = (j == 0) ? p0 : fast_sigmoid(gains[row[j - 1]]);
            if (j >= TH - 1) over = fmaf(dp[TH - 1], pj, over);
            const int kmax = (j + 1 < TH - 1) ? (j + 1) : (TH - 1);
            #pragma unroll
            for (int k = kmax; k >= 1; --k)
                dp[k] = fmaf(pj, dp[k - 1] - dp[k], dp[k]);
            dp[0] = fmaf(-pj, dp[0], dp[0]);
        }
        local = fmaf(0.25f, p0, -over);
    }
    #pragma unroll
    for (int o = 32; o > 0; o >>= 1) local += __shfl_down(local, o, 64);
    if ((tid & 63) == 0) s_red[tid >> 6] = local;
    __syncthreads();
    if (tid == 0) {
        float s = 0.0f;
        #pragma unroll
        for (int w = 0; w < FBLK / 64; ++w) s += s_red[w];
        atomicAdd(out, s);
    }
}

extern "C" void kernel_launch(void* const* d_in, const int* in_sizes, int n_in,
                              void* d_out, int out_size, void* d_ws, size_t ws_size,
                              hipStream_t stream) {
    const float* gains = (const float*)d_in[0];
    const int*   nbr   = (const int*)d_in[1];
    float*       out   = (float*)d_out;
    const int n = in_sizes[0];

    zero_out_kernel<<<1, 64, 0, stream>>>(out);

    if (ws_size >= (size_t)TBL) {
        unsigned char* tbl = (unsigned char*)d_ws;
        build_table_kernel<<<(TBL / 4 + 255) / 256, 256, 0, stream>>>(
            gains, (unsigned*)tbl, n);
        const int grid = (n + BLK - 1) / BLK;
        pgl_lds_kernel<<<grid, BLK, 0, stream>>>(gains, nbr, tbl, out, n);
    } else {
        const int grid = (n + FBLK - 1) / FBLK;
        pgl_direct_kernel<<<grid, FBLK, 0, stream>>>(gains, nbr, out, n);
    }
}

// Round 9
// 293.146 us; speedup vs baseline: 1.6559x; 1.6559x over previous
//
#include <hip/hip_runtime.h>

constexpr int DEG = 31;        // neighbors per node
constexpr int NEV = 32;        // events per node (self + neighbors)
constexpr int TH  = 16;        // threshold: dp[0..15] + absorbing "over"
constexpr int BLK = 256;
constexpr int TBL = 1 << 20;   // u8 table entries (padded >= n)

typedef int  vint4  __attribute__((ext_vector_type(4)));   // nt-compatible 16B vector

__global__ void zero_out_kernel(float* out) {
    if (threadIdx.x == 0) out[0] = 0.0f;
}

__device__ __forceinline__ float fast_sigmoid(float x) {
    return 1.0f / (1.0f + __expf(-x));
}

// ---- phase 1: u8 table tbl[i] = rint(sigmoid(gains[i])*255), packed stores ----
__global__ __launch_bounds__(256)
void build_table_kernel(const float* __restrict__ gains,
                        unsigned* __restrict__ tbl4, int n) {
    const int t = blockIdx.x * 256 + threadIdx.x;   // entries 4t..4t+3
    if (t < TBL / 4) {
        unsigned w = 0;
        #pragma unroll
        for (int k = 0; k < 4; ++k) {
            const int i = 4 * t + k;
            const float p = (i < n) ? fast_sigmoid(gains[i]) : 0.0f;
            const unsigned b = __float2uint_rn(p * 255.0f);
            w |= (b & 0xFFu) << (8 * k);
        }
        tbl4[t] = w;
    }
}

// ---- phase 2: direct gather from the L2-pinned 1 MB u8 table ----
// Streaming traffic (neighbor lists, self gains) uses nt loads so it cannot
// evict the table from L2: r5 proved nt bypasses L2 allocation entirely.
__global__ __launch_bounds__(BLK)
void pgl_kernel(const float* __restrict__ gains,
                const int*   __restrict__ nbr,
                const unsigned char* __restrict__ tbl,
                float*       __restrict__ out, int n) {
    __shared__ int s_idx[BLK * DEG];          // 31744 B
    __shared__ float s_red[BLK / 64];

    const int tid        = threadIdx.x;
    const int blockStart = blockIdx.x * BLK;

    // ---- stage neighbor rows via nt 16B loads (zero-reuse stream) ----
    const int rows  = min(BLK, n - blockStart);
    const int elems = rows * DEG;
    const int base  = blockStart * DEG;
    {
        const vint4* nb4 = (const vint4*)(nbr + base);
        vint4*       s4  = (vint4*)s_idx;
        const int nvec   = elems >> 2;
        for (int v = tid; v < nvec; v += BLK)
            s4[v] = __builtin_nontemporal_load(nb4 + v);
        for (int e = (nvec << 2) + tid; e < elems; e += BLK)
            s_idx[e] = __builtin_nontemporal_load(nbr + base + e);
    }
    __syncthreads();

    float local = 0.0f;
    const int i = blockStart + tid;
    if (i < n) {
        const int* row = s_idx + tid * DEG;   // stride-31 LDS: 2-way alias (free)

        // ---- 31 random u8 gathers from the L2-resident table ----
        unsigned gb[DEG];
        #pragma unroll
        for (int j = 0; j < DEG; ++j) gb[j] = tbl[(unsigned)row[j]];

        // ---- self probability in fp32 (nt: gains is a one-pass stream) ----
        const float p0 = fast_sigmoid(__builtin_nontemporal_load(gains + i));

        // ---- absorbing-state Poisson-binomial DP ----
        float dp[TH];
        dp[0] = 1.0f;
        #pragma unroll
        for (int k = 1; k < TH; ++k) dp[k] = 0.0f;
        float over = 0.0f;

        #pragma unroll
        for (int j = 0; j < NEV; ++j) {
            const float pj = (j == 0) ? p0 : (float)gb[j - 1] * (1.0f / 255.0f);
            if (j >= TH - 1) over = fmaf(dp[TH - 1], pj, over);
            const int kmax = (j + 1 < TH - 1) ? (j + 1) : (TH - 1);
            #pragma unroll
            for (int k = kmax; k >= 1; --k)
                dp[k] = fmaf(pj, dp[k - 1] - dp[k], dp[k]);
            dp[0] = fmaf(-pj, dp[0], dp[0]);
        }
        local = fmaf(0.25f, p0, -over);       // -(loss) contribution
    }

    // ---- block reduction: wave shuffle -> LDS -> one atomic per block ----
    #pragma unroll
    for (int o = 32; o > 0; o >>= 1) local += __shfl_down(local, o, 64);
    if ((tid & 63) == 0) s_red[tid >> 6] = local;
    __syncthreads();
    if (tid == 0) {
        float s = 0.0f;
        #pragma unroll
        for (int w = 0; w < BLK / 64; ++w) s += s_red[w];
        atomicAdd(out, s);
    }
}

// ---- fallback (ws too small): f32 direct gather, round-1 structure ----
__global__ __launch_bounds__(BLK)
void pgl_direct_kernel(const float* __restrict__ gains,
                       const int*   __restrict__ nbr,
                       float*       __restrict__ out, int n) {
    __shared__ int s_idx[BLK * DEG];
    __shared__ float s_red[BLK / 64];
    const int tid = threadIdx.x;
    const int blockStart = blockIdx.x * BLK;
    const int rows  = min(BLK, n - blockStart);
    const int elems = rows * DEG;
    const int base  = blockStart * DEG;
    const int4* nb4 = (const int4*)(nbr + base);
    int4* s4 = (int4*)s_idx;
    const int nvec = elems >> 2;
    for (int v = tid; v < nvec; v += BLK) s4[v] = nb4[v];
    for (int e = (nvec << 2) + tid; e < elems; e += BLK) s_idx[e] = nbr[base + e];
    __syncthreads();
    float local = 0.0f;
    const int i = blockStart + tid;
    if (i < n) {
        const int* row = s_idx + tid * DEG;
        float dp[TH];
        dp[0] = 1.0f;
        #pragma unroll
        for (int k = 1; k < TH; ++k) dp[k] = 0.0f;
        float over = 0.0f;
        const float p0 = fast_sigmoid(gains[i]);
        #pragma unroll
        for (int j = 0; j < NEV; ++j) {
            const float pj = (j == 0) ? p0 : fast_sigmoid(gains[row[j - 1]]);
            if (j >= TH - 1) over = fmaf(dp[TH - 1], pj, over);
            const int kmax = (j + 1 < TH - 1) ? (j + 1) : (TH - 1);
            #pragma unroll
            for (int k = kmax; k >= 1; --k)
                dp[k] = fmaf(pj, dp[k - 1] - dp[k], dp[k]);
            dp[0] = fmaf(-pj, dp[0], dp[0]);
        }
        local = fmaf(0.25f, p0, -over);
    }
    #pragma unroll
    for (int o = 32; o > 0; o >>= 1) local += __shfl_down(local, o, 64);
    if ((tid & 63) == 0) s_red[tid >> 6] = local;
    __syncthreads();
    if (tid == 0) {
        float s = 0.0f;
        #pragma unroll
        for (int w = 0; w < BLK / 64; ++w) s += s_red[w];
        atomicAdd(out, s);
    }
}

extern "C" void kernel_launch(void* const* d_in, const int* in_sizes, int n_in,
                              void* d_out, int out_size, void* d_ws, size_t ws_size,
                              hipStream_t stream) {
    const float* gains = (const float*)d_in[0];
    const int*   nbr   = (const int*)d_in[1];
    float*       out   = (float*)d_out;
    const int n = in_sizes[0];

    zero_out_kernel<<<1, 64, 0, stream>>>(out);

    const int grid = (n + BLK - 1) / BLK;
    if (ws_size >= (size_t)TBL && n <= TBL) {
        unsigned char* tbl = (unsigned char*)d_ws;
        build_table_kernel<<<(TBL / 4 + 255) / 256, 256, 0, stream>>>(
            gains, (unsigned*)tbl, n);
        pgl_kernel<<<grid, BLK, 0, stream>>>(gains, nbr, tbl, out, n);
    } else {
        pgl_direct_kernel<<<grid, BLK, 0, stream>>>(gains, nbr, out, n);
    }
}